// Round 3
// baseline (3007.740 us; speedup 1.0000x reference)
//
#include <hip/hip_runtime.h>
#include <stdint.h>

typedef __bf16 bf16;
typedef __bf16 bf16x8 __attribute__((ext_vector_type(8)));
typedef float floatx4 __attribute__((ext_vector_type(4)));

#define EPS 1e-5f

__device__ __forceinline__ float wave_red_sum(float v) {
#pragma unroll
  for (int off = 32; off; off >>= 1) v += __shfl_xor(v, off, 64);
  return v;
}
__device__ __forceinline__ float wave_red_max(float v) {
#pragma unroll
  for (int off = 32; off; off >>= 1) v = fmaxf(v, __shfl_xor(v, off, 64));
  return v;
}
__device__ __forceinline__ float sigmoidf(float x) { return 1.f / (1.f + expf(-x)); }

// ---------------- weight transpose + cast: in fp32 [R,C] -> out bf16 [C,R] -------------
__global__ __launch_bounds__(256) void transpose_cast_kernel(
    const float* __restrict__ in, bf16* __restrict__ out, int R, int C) {
  __shared__ float tile[32][33];
  const size_t boff = (size_t)blockIdx.z * R * C;
  in += boff; out += boff;
  int tx = threadIdx.x, ty = threadIdx.y;
  int c0 = blockIdx.x * 32, r0 = blockIdx.y * 32;
#pragma unroll
  for (int j = 0; j < 32; j += 8)
    tile[ty + j][tx] = in[(size_t)(r0 + ty + j) * C + c0 + tx];
  __syncthreads();
#pragma unroll
  for (int j = 0; j < 32; j += 8)
    out[(size_t)(c0 + ty + j) * R + r0 + tx] = (bf16)tile[tx][ty + j];
}

// ---------------- direct-from-L2 MFMA GEMM (no LDS in K-loop).
// C = A[M,K] @ Bt[N,K]^T + bias. MODE0: gelu -> bf16. MODE1: bf16 + colsum atomics into gsum.
template <int BM, int BN, int WM, int WN, int K, int MODE>
__global__ __launch_bounds__(256) void gemm_direct_kernel(
    const bf16* __restrict__ A, const bf16* __restrict__ Bt,
    const float* __restrict__ bias, bf16* __restrict__ outb,
    float* __restrict__ gsum, int N) {
  constexpr int MI = WM / 16, NI = WN / 16, NWC = BN / WN;
  const int tid = threadIdx.x, l = tid & 63, w = tid >> 6;
  const int wr = w / NWC, wc = w % NWC;
  const int m0 = blockIdx.y * BM, n0 = blockIdx.x * BN;
  const int quad = l >> 4, lane16 = l & 15;

  const bf16* Ap[MI];
  const bf16* Bp[NI];
#pragma unroll
  for (int mi = 0; mi < MI; ++mi)
    Ap[mi] = A + (size_t)(m0 + wr * WM + mi * 16 + lane16) * K + quad * 8;
#pragma unroll
  for (int ni = 0; ni < NI; ++ni)
    Bp[ni] = Bt + (size_t)(n0 + wc * WN + ni * 16 + lane16) * K + quad * 8;

  floatx4 acc[MI][NI];
#pragma unroll
  for (int mi = 0; mi < MI; ++mi)
#pragma unroll
    for (int ni = 0; ni < NI; ++ni) acc[mi][ni] = (floatx4){0.f, 0.f, 0.f, 0.f};

  for (int kb = 0; kb < K; kb += 256) {
#pragma unroll
    for (int ku = 0; ku < 256; ku += 32) {
      bf16x8 af[MI], bfv[NI];
#pragma unroll
      for (int mi = 0; mi < MI; ++mi) af[mi] = *(const bf16x8*)(Ap[mi] + kb + ku);
#pragma unroll
      for (int ni = 0; ni < NI; ++ni) bfv[ni] = *(const bf16x8*)(Bp[ni] + kb + ku);
#pragma unroll
      for (int mi = 0; mi < MI; ++mi)
#pragma unroll
        for (int ni = 0; ni < NI; ++ni)
          acc[mi][ni] = __builtin_amdgcn_mfma_f32_16x16x32_bf16(af[mi], bfv[ni], acc[mi][ni], 0, 0, 0);
    }
  }

  float psum[NI];
#pragma unroll
  for (int ni = 0; ni < NI; ++ni) psum[ni] = 0.f;

#pragma unroll
  for (int ni = 0; ni < NI; ++ni) {
    const int gn = n0 + wc * WN + ni * 16 + lane16;
    const float bv = bias[gn];
#pragma unroll
    for (int mi = 0; mi < MI; ++mi) {
#pragma unroll
      for (int i = 0; i < 4; ++i) {
        const int gm = m0 + wr * WM + mi * 16 + quad * 4 + i;
        float v = acc[mi][ni][i] + bv;
        if constexpr (MODE == 0) {
          float ge = 0.5f * v * (1.f + erff(v * 0.7071067811865475f));
          outb[(size_t)gm * N + gn] = (bf16)ge;
        } else {
          outb[(size_t)gm * N + gn] = (bf16)v;
          psum[ni] += v;
        }
      }
    }
  }
  if constexpr (MODE == 1) {
    __shared__ float cs[BN];
    __syncthreads();
    for (int t = tid; t < BN; t += 256) cs[t] = 0.f;
    __syncthreads();
#pragma unroll
    for (int ni = 0; ni < NI; ++ni)
      atomicAdd(&cs[wc * WN + ni * 16 + lane16], psum[ni]);
    __syncthreads();
    for (int t = tid; t < BN; t += 256) atomicAdd(&gsum[n0 + t], cs[t]);
  }
}

// ---------------- split-K atomic GEMV: out[z,col] += alpha * sum_k v[z,k]*M[z][k*N+col]
__global__ __launch_bounds__(256) void gemv_kernel(
    const float* __restrict__ vin, int vstride, const float* __restrict__ M,
    size_t mstride, int K, int N, float alpha, float* __restrict__ outp,
    int ostride) {
  const int l = threadIdx.x & 63, wv = threadIdx.x >> 6;
  const int col = blockIdx.x * 64 + l;
  const int KS = gridDim.y;
  const int Kc = (K + KS - 1) / KS;
  const int k0 = blockIdx.y * Kc;
  const int k1 = min(K, k0 + Kc);
  const float* v = vin + (size_t)blockIdx.z * vstride;
  const float* Mp = M + (size_t)blockIdx.z * mstride;
  float acc = 0.f;
  for (int k = k0 + wv; k < k1; k += 4)
    acc += v[k] * Mp[(size_t)k * N + col];
  __shared__ float sh[4][64];
  sh[wv][l] = acc;
  __syncthreads();
  if (wv == 0) {
    float r = (sh[0][l] + sh[1][l] + sh[2][l] + sh[3][l]) * alpha;
    atomicAdd(&outp[(size_t)blockIdx.z * ostride + col], r);
  }
}

// ---------------- fused small gemvs after GEMM2: gate_pre (z=0,1) and ubuf (z=2..4)
__global__ __launch_bounds__(256) void small_gemvs_kernel(
    const float* __restrict__ regs, const float* __restrict__ summary,
    const float* __restrict__ gwp, const float* __restrict__ gbp,
    const float* __restrict__ wpp, float* __restrict__ gate_pre,
    float* __restrict__ ubuf) {
  const int z = blockIdx.z;
  const float* v;
  const float* M;
  float* outp;
  int K, N;
  float alpha;
  if (z == 0)      { v = regs;    M = gwp;             outp = gate_pre; K = 768; N = 512; alpha = 1.f; }
  else if (z == 1) { v = summary; M = gwp + 768 * 512; outp = gate_pre; K = 512; N = 512; alpha = 1.f / 8192.f; }
  else { int r = z - 2; v = summary; M = wpp + (size_t)r * 512 * 256; outp = ubuf + r * 256; K = 512; N = 256; alpha = 1.f / 8192.f; }
  const int l = threadIdx.x & 63, wv = threadIdx.x >> 6;
  const int col = blockIdx.x * 64 + l;
  if (blockIdx.x * 64 >= N) return;  // block-uniform guard
  const int Kc = K / 8;
  const int k0 = blockIdx.y * Kc, k1 = k0 + Kc;
  float acc = 0.f;
  for (int k = k0 + wv; k < k1; k += 4)
    acc += v[k] * M[(size_t)k * N + col];
  __shared__ float sh[4][64];
  sh[wv][l] = acc;
  __syncthreads();
  if (wv == 0) {
    float r = (sh[0][l] + sh[1][l] + sh[2][l] + sh[3][l]) * alpha;
    if (z == 0 && blockIdx.y == 0) r += gbp[col];
    atomicAdd(&outp[col], r);
  }
}

// ---------------- init helper: a[na]=0, b[nb]=0, c[nc]=csrc?csrc:0
__global__ __launch_bounds__(256) void init3_kernel(
    float* __restrict__ a, int na, float* __restrict__ b, int nb,
    float* __restrict__ c, const float* __restrict__ csrc, int nc) {
  const int t = blockIdx.x * 256 + threadIdx.x;
  if (t < na) a[t] = 0.f;
  if (t < nb) b[t] = 0.f;
  if (t < nc) c[t] = csrc ? csrc[t] : 0.f;
}

// ---------------- standalone LN + cast (first phase only); block 0 zeroes phase buffers
__global__ __launch_bounds__(256) void ln_cast_kernel(
    const float* __restrict__ res, const float* __restrict__ s,
    const float* __restrict__ b, bf16* __restrict__ xn,
    float* __restrict__ summary, float* __restrict__ gp0,
    float* __restrict__ gp1, float* __restrict__ ubuf) {
  if (blockIdx.x == 0) {
    const int t = threadIdx.x;
    summary[t] = 0.f; summary[t + 256] = 0.f;
    gp0[t] = 0.f; gp0[t + 256] = 0.f;
    gp1[t] = 0.f; gp1[t + 256] = 0.f;
    ubuf[t] = 0.f; ubuf[t + 256] = 0.f; ubuf[t + 512] = 0.f;
  }
  const int wid = threadIdx.x >> 6, l = threadIdx.x & 63;
  const int row = blockIdx.x * 4 + wid;
  const int cb = l * 8;
  const float* x = res + (size_t)row * 512 + cb;
  float4 a0 = *(const float4*)x, a1 = *(const float4*)(x + 4);
  float v[8] = {a0.x, a0.y, a0.z, a0.w, a1.x, a1.y, a1.z, a1.w};
  float sum = 0.f, sq = 0.f;
#pragma unroll
  for (int j = 0; j < 8; ++j) { sum += v[j]; sq += v[j] * v[j]; }
  sum = wave_red_sum(sum); sq = wave_red_sum(sq);
  float m = sum * (1.f / 512.f);
  float rstd = rsqrtf(sq * (1.f / 512.f) - m * m + EPS);
  bf16x8 o;
#pragma unroll
  for (int j = 0; j < 8; ++j) o[j] = (bf16)((v[j] - m) * rstd * s[cb + j] + b[cb + j]);
  *(bf16x8*)(xn + (size_t)row * 512 + cb) = o;
}

// ---------------- fused residual update + LN/cast for the NEXT phase
__global__ __launch_bounds__(256) void resid_ln_kernel(
    float* __restrict__ res, const bf16* __restrict__ delta,
    const float* __restrict__ gp, const float* __restrict__ passw, int p,
    const float* __restrict__ s, const float* __restrict__ b,
    bf16* __restrict__ xn) {
  const int wid = threadIdx.x >> 6, l = threadIdx.x & 63;
  const int row = blockIdx.x * 4 + wid;
  const int cb = l * 8;
  const float pw = passw[p];
  float* x = res + (size_t)row * 512 + cb;
  float4 a0 = *(const float4*)x, a1 = *(const float4*)(x + 4);
  bf16x8 dv = *(const bf16x8*)(delta + (size_t)row * 512 + cb);
  float4 g0 = *(const float4*)(gp + cb), g1 = *(const float4*)(gp + cb + 4);
  float gg[8] = {g0.x, g0.y, g0.z, g0.w, g1.x, g1.y, g1.z, g1.w};
  float v[8] = {a0.x, a0.y, a0.z, a0.w, a1.x, a1.y, a1.z, a1.w};
#pragma unroll
  for (int j = 0; j < 8; ++j) v[j] += pw * sigmoidf(gg[j]) * (float)dv[j];
  *(float4*)x = make_float4(v[0], v[1], v[2], v[3]);
  *(float4*)(x + 4) = make_float4(v[4], v[5], v[6], v[7]);
  float sum = 0.f, sq = 0.f;
#pragma unroll
  for (int j = 0; j < 8; ++j) { sum += v[j]; sq += v[j] * v[j]; }
  sum = wave_red_sum(sum); sq = wave_red_sum(sq);
  float m = sum * (1.f / 512.f);
  float rstd = rsqrtf(sq * (1.f / 512.f) - m * m + EPS);
  bf16x8 o;
#pragma unroll
  for (int j = 0; j < 8; ++j) o[j] = (bf16)((v[j] - m) * rstd * s[cb + j] + b[cb + j]);
  *(bf16x8*)(xn + (size_t)row * 512 + cb) = o;
}

// ---------------- attention logits: one wave per row; block 0 zeroes c[2048]
__global__ __launch_bounds__(256) void attn_logits_kernel(
    const float* __restrict__ res, const float* __restrict__ s,
    const float* __restrict__ b, const float* __restrict__ kq,
    float* __restrict__ logits, float* __restrict__ czero) {
  if (blockIdx.x == 0) {
#pragma unroll
    for (int j = 0; j < 8; ++j) czero[threadIdx.x * 8 + j] = 0.f;
  }
  const int wid = threadIdx.x >> 6, l = threadIdx.x & 63;
  const int row = blockIdx.x * 4 + wid;
  const int cb = l * 8;
  const float* x = res + (size_t)row * 512 + cb;
  float4 a0 = *(const float4*)x, a1 = *(const float4*)(x + 4);
  float v[8] = {a0.x, a0.y, a0.z, a0.w, a1.x, a1.y, a1.z, a1.w};
  float sum = 0.f, sq = 0.f;
#pragma unroll
  for (int j = 0; j < 8; ++j) { sum += v[j]; sq += v[j] * v[j]; }
  sum = wave_red_sum(sum); sq = wave_red_sum(sq);
  float m = sum * (1.f / 512.f);
  float rstd = rsqrtf(sq * (1.f / 512.f) - m * m + EPS);
  float dot = 0.f;
#pragma unroll
  for (int j = 0; j < 8; ++j)
    dot += ((v[j] - m) * rstd * s[cb + j] + b[cb + j]) * kq[cb + j];
  dot = wave_red_sum(dot);
  if (l == 0) logits[row] = dot;
}

// ---------------- softmax over 2048 per batch
__global__ __launch_bounds__(256) void softmax_kernel(float* __restrict__ attn) {
  __shared__ float red[4];
  const int t = threadIdx.x;
  float* p = attn + blockIdx.x * 2048;
  float v[8];
#pragma unroll
  for (int j = 0; j < 8; ++j) v[j] = p[t * 8 + j];
  float mx = v[0];
#pragma unroll
  for (int j = 1; j < 8; ++j) mx = fmaxf(mx, v[j]);
  mx = wave_red_max(mx);
  if ((t & 63) == 0) red[t >> 6] = mx;
  __syncthreads();
  mx = fmaxf(fmaxf(red[0], red[1]), fmaxf(red[2], red[3]));
  __syncthreads();
  float s = 0.f;
#pragma unroll
  for (int j = 0; j < 8; ++j) { v[j] = expf(v[j] - mx); s += v[j]; }
  s = wave_red_sum(s);
  if ((t & 63) == 0) red[t >> 6] = s;
  __syncthreads();
  float inv = 1.f / (red[0] + red[1] + red[2] + red[3]);
#pragma unroll
  for (int j = 0; j < 8; ++j) p[t * 8 + j] = v[j] * inv;
}

// ---------------- weighted row-sum of LN(res); attn==null -> uniform 1/2048
__global__ __launch_bounds__(256) void wsum_kernel(
    const float* __restrict__ res, const float* __restrict__ s,
    const float* __restrict__ b, const float* __restrict__ attn,
    float* __restrict__ cout, int per_batch) {
  __shared__ float csh[512];
  const int tid = threadIdx.x, l = tid & 63, wv = tid >> 6;
  for (int t = tid; t < 512; t += 256) csh[t] = 0.f;
  __syncthreads();
  const int cb = l * 8;
  float sl[8], bl[8];
#pragma unroll
  for (int j = 0; j < 8; ++j) { sl[j] = s[cb + j]; bl[j] = b[cb + j]; }
  float pf[8] = {};
  const int base_row = blockIdx.x * 32;
  for (int rr = wv; rr < 32; rr += 4) {
    int row = base_row + rr;
    const float* x = res + (size_t)row * 512 + cb;
    float4 a0 = *(const float4*)x, a1 = *(const float4*)(x + 4);
    float v[8] = {a0.x, a0.y, a0.z, a0.w, a1.x, a1.y, a1.z, a1.w};
    float sum = 0.f, sq = 0.f;
#pragma unroll
    for (int j = 0; j < 8; ++j) { sum += v[j]; sq += v[j] * v[j]; }
    sum = wave_red_sum(sum); sq = wave_red_sum(sq);
    float m = sum * (1.f / 512.f);
    float rstd = rsqrtf(sq * (1.f / 512.f) - m * m + EPS);
    float aw = attn ? attn[row] : (1.f / 2048.f);
#pragma unroll
    for (int j = 0; j < 8; ++j) pf[j] += aw * ((v[j] - m) * rstd * sl[j] + bl[j]);
  }
#pragma unroll
  for (int j = 0; j < 8; ++j) atomicAdd(&csh[cb + j], pf[j]);
  __syncthreads();
  float* outp = cout + (per_batch ? (blockIdx.x >> 6) * 512 : 0);
  for (int t = tid; t < 512; t += 256) atomicAdd(&outp[t], csh[t]);
}

// ---------------- kq = scale * (KM @ q), one wave per row
__global__ __launch_bounds__(256) void kq_kernel(
    const float* __restrict__ KM, const float* __restrict__ q, float scale,
    float* __restrict__ kq) {
  const int d = blockIdx.x * 4 + (threadIdx.x >> 6), l = threadIdx.x & 63;
  float a = 0.f;
  for (int j = l; j < 512; j += 64) a += KM[(size_t)d * 512 + j] * q[j];
  a = wave_red_sum(a);
  if (l == 0) kq[d] = a * scale;
}

// ---------------- regsB = regsA + wg*ubuf; then zero summary/ubuf/gp_next for next phase
__global__ __launch_bounds__(256) void reg_final_kernel(
    const float* __restrict__ regsA, float* __restrict__ ubuf,
    float* __restrict__ summary, const float* __restrict__ wgw,
    const float* __restrict__ wgb, float* __restrict__ regsB,
    float* __restrict__ gp_next) {
  __shared__ float wg[3];
  const int l = threadIdx.x & 63, wv = threadIdx.x >> 6;
  if (wv < 3) {
    float sg = 0.f;
    for (int d = l; d < 512; d += 64) sg += summary[d] * wgw[wv * 512 + d];
    sg = wave_red_sum(sg) * (1.f / 8192.f);
    if (l == 0) wg[wv] = sigmoidf(sg + wgb[wv]);
  }
  __syncthreads();
  for (int j = threadIdx.x; j < 768; j += 256)
    regsB[j] = regsA[j] + wg[j >> 8] * ubuf[j];
  __syncthreads();
  const int t = threadIdx.x;
  summary[t] = 0.f; summary[t + 256] = 0.f;
  gp_next[t] = 0.f; gp_next[t + 256] = 0.f;
  ubuf[t] = 0.f; ubuf[t + 256] = 0.f; ubuf[t + 512] = 0.f;
}

// ---------------- pass_w = sigmoid(tile(reg_init,5) @ ms3_w + ms3_b)
__global__ __launch_bounds__(64) void passw_kernel(
    const float* __restrict__ reg_init, const float* __restrict__ ms3_w,
    const float* __restrict__ ms3_b, float* __restrict__ pass_w) {
  const int l = threadIdx.x;
  float acc[5] = {};
  for (int i = l; i < 3840; i += 64) {
    float v = reg_init[i % 768];
#pragma unroll
    for (int p = 0; p < 5; ++p) acc[p] += v * ms3_w[i * 5 + p];
  }
#pragma unroll
  for (int p = 0; p < 5; ++p) acc[p] = wave_red_sum(acc[p]);
  if (l < 5) pass_w[l] = sigmoidf(acc[l] + ms3_b[l]);
}

// ---------------- final: out = LN(res + outv[b]; out_ln)
__global__ __launch_bounds__(256) void final_out_kernel(
    const float* __restrict__ res, const float* __restrict__ outv,
    const float* __restrict__ s, const float* __restrict__ b,
    float* __restrict__ out) {
  const int wid = threadIdx.x >> 6, l = threadIdx.x & 63;
  const int row = blockIdx.x * 4 + wid;
  const int bidx = row >> 11, cb = l * 8;
  const float* x = res + (size_t)row * 512 + cb;
  const float* ov = outv + bidx * 512 + cb;
  float4 a0 = *(const float4*)x, a1 = *(const float4*)(x + 4);
  float v[8] = {a0.x, a0.y, a0.z, a0.w, a1.x, a1.y, a1.z, a1.w};
#pragma unroll
  for (int j = 0; j < 8; ++j) v[j] += ov[j];
  float sum = 0.f, sq = 0.f;
#pragma unroll
  for (int j = 0; j < 8; ++j) { sum += v[j]; sq += v[j] * v[j]; }
  sum = wave_red_sum(sum); sq = wave_red_sum(sq);
  float m = sum * (1.f / 512.f);
  float rstd = rsqrtf(sq * (1.f / 512.f) - m * m + EPS);
  float o[8];
#pragma unroll
  for (int j = 0; j < 8; ++j) o[j] = (v[j] - m) * rstd * s[cb + j] + b[cb + j];
  float* op = out + (size_t)row * 512 + cb;
  *(float4*)op = make_float4(o[0], o[1], o[2], o[3]);
  *(float4*)(op + 4) = make_float4(o[4], o[5], o[6], o[7]);
}

extern "C" void kernel_launch(void* const* d_in, const int* in_sizes, int n_in,
                              void* d_out, int out_size, void* d_ws, size_t ws_size,
                              hipStream_t stream) {
  const float* x        = (const float*)d_in[0];
  const float* reg_init = (const float*)d_in[1];
  const float* ffn_ln_s = (const float*)d_in[2];
  const float* ffn_ln_b = (const float*)d_in[3];
  const float* ffn_w1   = (const float*)d_in[4];
  const float* ffn_b1   = (const float*)d_in[5];
  const float* ffn_w2   = (const float*)d_in[6];
  const float* ffn_b2   = (const float*)d_in[7];
  const float* gate_w   = (const float*)d_in[8];
  const float* gate_b   = (const float*)d_in[9];
  const float* wproj_w  = (const float*)d_in[10];
  const float* wgate_w  = (const float*)d_in[11];
  const float* wgate_b  = (const float*)d_in[12];
  const float* s4_q     = (const float*)d_in[13];
  const float* s4_k     = (const float*)d_in[14];
  const float* s4_v     = (const float*)d_in[15];
  const float* s4_sum   = (const float*)d_in[16];
  const float* s4_ln_s  = (const float*)d_in[17];
  const float* s4_ln_b  = (const float*)d_in[18];
  const float* ms3_w    = (const float*)d_in[19];
  const float* ms3_b    = (const float*)d_in[20];
  const float* m4_q     = (const float*)d_in[21];
  const float* m4_k     = (const float*)d_in[22];
  const float* m4_v     = (const float*)d_in[23];
  const float* m4_out   = (const float*)d_in[24];
  const float* m4_ln_s  = (const float*)d_in[25];
  const float* m4_ln_b  = (const float*)d_in[26];
  const float* out_ln_s = (const float*)d_in[27];
  const float* out_ln_b = (const float*)d_in[28];
  float* out = (float*)d_out;

  char* wsp = (char*)d_ws;
  auto take = [&](size_t n) { char* p = wsp; wsp += (n + 255) & ~(size_t)255; return p; };
  float* residual = (float*)take(8192ull * 512 * 4);
  bf16*  xn       = (bf16*) take(8192ull * 512 * 2);
  bf16*  hbuf     = (bf16*) take(8192ull * 1536 * 2);
  bf16*  delta    = (bf16*) take(8192ull * 512 * 2);
  bf16*  w1t      = (bf16*) take(3ull * 1536 * 512 * 2);
  bf16*  w2t      = (bf16*) take(3ull * 512 * 1536 * 2);
  float* attn     = (float*)take(8192 * 4);
  float* cacc     = (float*)take(2048 * 4);
  float* qbuf     = (float*)take(512 * 4);
  float* kqbuf    = (float*)take(512 * 4);
  float* summary  = (float*)take(512 * 4);
  float* gp0      = (float*)take(512 * 4);
  float* gp1      = (float*)take(512 * 4);
  float* ubuf     = (float*)take(768 * 4);
  float* regsA    = (float*)take(768 * 4);
  float* regsB    = (float*)take(768 * 4);
  float* banks    = (float*)take(5 * 768 * 4);
  float* passw    = (float*)take(64);
  float* summv    = (float*)take(4 * 512 * 4);
  float* outv     = (float*)take(4 * 512 * 4);
  float* gpbuf[2] = {gp0, gp1};

  hipMemcpyAsync(residual, x, 8192ull * 512 * 4, hipMemcpyDeviceToDevice, stream);
  transpose_cast_kernel<<<dim3(1536 / 32, 512 / 32, 3), dim3(32, 8), 0, stream>>>(ffn_w1, w1t, 512, 1536);
  transpose_cast_kernel<<<dim3(512 / 32, 1536 / 32, 3), dim3(32, 8), 0, stream>>>(ffn_w2, w2t, 1536, 512);
  passw_kernel<<<1, 64, 0, stream>>>(reg_init, ms3_w, ms3_b, passw);
  // first-phase LN + zero phase buffers
  ln_cast_kernel<<<2048, 256, 0, stream>>>(residual, ffn_ln_s, ffn_ln_b, xn, summary, gp0, gp1, ubuf);

  const float scale = 0.04419417382415922f;  // 512^-0.5

  for (int p = 0; p < 5; ++p) {
    // s4_read
    if (p == 0) {
      // q = 0 exactly -> uniform attention; just zero cacc/summv, regsA=reg_init
      init3_kernel<<<8, 256, 0, stream>>>(cacc, 2048, summv, 512, regsA, reg_init, 768);
      wsum_kernel<<<256, 256, 0, stream>>>(residual, s4_ln_s, s4_ln_b, nullptr, cacc, 0);
    } else {
      init3_kernel<<<8, 256, 0, stream>>>(qbuf, 512, summv, 512, regsA, reg_init, 768);
      gemv_kernel<<<dim3(8, 4 * (p + 1), 1), 256, 0, stream>>>(banks, 0, s4_q, 0, p * 768, 512, 1.f, qbuf, 0);
      kq_kernel<<<128, 256, 0, stream>>>(s4_k, qbuf, scale, kqbuf);
      attn_logits_kernel<<<2048, 256, 0, stream>>>(residual, s4_ln_s, s4_ln_b, kqbuf, attn, cacc);
      softmax_kernel<<<4, 256, 0, stream>>>(attn);
      wsum_kernel<<<256, 256, 0, stream>>>(residual, s4_ln_s, s4_ln_b, attn, cacc, 0);
    }
    gemv_kernel<<<dim3(8, 8, 1), 256, 0, stream>>>(cacc, 0, s4_v, 0, 512, 512, 0.25f, summv, 0);
    gemv_kernel<<<dim3(12, 8, 1), 256, 0, stream>>>(summv, 0, s4_sum, 0, 512, 768, 1.f, regsA, 0);

    float* cur = regsA;
    float* nxt = regsB;
    for (int ph = 0; ph < 3; ++ph) {
      const int pp = p * 3 + ph;
      gemm_direct_kernel<128, 128, 64, 64, 512, 0><<<dim3(12, 64), 256, 0, stream>>>(
          xn, w1t + (size_t)ph * 1536 * 512, ffn_b1 + ph * 1536, hbuf, nullptr, 1536);
      gemm_direct_kernel<128, 64, 64, 32, 1536, 1><<<dim3(8, 64), 256, 0, stream>>>(
          hbuf, w2t + (size_t)ph * 512 * 1536, ffn_b2 + ph * 512, delta, summary, 512);
      small_gemvs_kernel<<<dim3(8, 8, 5), 256, 0, stream>>>(
          cur, summary, gate_w + (size_t)pp * 1280 * 512, gate_b + pp * 512,
          wproj_w + (size_t)pp * 3 * 512 * 256, gpbuf[pp & 1], ubuf);
      float* nx = (ph == 2) ? (banks + p * 768) : nxt;
      reg_final_kernel<<<1, 256, 0, stream>>>(cur, ubuf, summary, wgate_w + pp * 3 * 512,
                                              wgate_b + pp * 3, nx, gpbuf[(pp + 1) & 1]);
      // fused residual update + LN for next phase ((ph+1)%3; at pp=14 output unused)
      const int nph = (ph + 1) % 3;
      resid_ln_kernel<<<2048, 256, 0, stream>>>(residual, delta, gpbuf[pp & 1], passw, p,
                                                ffn_ln_s + nph * 512, ffn_ln_b + nph * 512, xn);
      float* t = cur; cur = nx; nxt = (ph == 0) ? regsA : regsB; (void)t;
    }
  }

  // MetaS4
  init3_kernel<<<8, 256, 0, stream>>>(qbuf, 512, summv, 2048, outv, nullptr, 2048);
  gemv_kernel<<<dim3(8, 16, 1), 256, 0, stream>>>(banks, 0, m4_q, 0, 3840, 512, 1.f, qbuf, 0);
  kq_kernel<<<128, 256, 0, stream>>>(m4_k, qbuf, scale, kqbuf);
  attn_logits_kernel<<<2048, 256, 0, stream>>>(residual, m4_ln_s, m4_ln_b, kqbuf, attn, cacc);
  softmax_kernel<<<4, 256, 0, stream>>>(attn);
  wsum_kernel<<<256, 256, 0, stream>>>(residual, m4_ln_s, m4_ln_b, attn, cacc, 1);
  gemv_kernel<<<dim3(8, 8, 4), 256, 0, stream>>>(cacc, 512, m4_v, 0, 512, 512, 1.f, summv, 512);
  gemv_kernel<<<dim3(8, 8, 4), 256, 0, stream>>>(summv, 512, m4_out, 0, 512, 512, 1.f, outv, 512);
  final_out_kernel<<<2048, 256, 0, stream>>>(residual, outv, out_ln_s, out_ln_b, out);
}

// Round 4
// 1705.800 us; speedup vs baseline: 1.7632x; 1.7632x over previous
//
#include <hip/hip_runtime.h>
#include <stdint.h>

typedef __bf16 bf16;
typedef __bf16 bf16x8 __attribute__((ext_vector_type(8)));
typedef float floatx4 __attribute__((ext_vector_type(4)));

#define EPS 1e-5f

__device__ __forceinline__ float wave_red_sum(float v) {
#pragma unroll
  for (int off = 32; off; off >>= 1) v += __shfl_xor(v, off, 64);
  return v;
}
__device__ __forceinline__ float wave_red_max(float v) {
#pragma unroll
  for (int off = 32; off; off >>= 1) v = fmaxf(v, __shfl_xor(v, off, 64));
  return v;
}
__device__ __forceinline__ float sigmoidf(float x) { return 1.f / (1.f + expf(-x)); }

__device__ __forceinline__ void gload_lds16(const bf16* g, bf16* l) {
  __builtin_amdgcn_global_load_lds(
      (const __attribute__((address_space(1))) char*)(g),
      (__attribute__((address_space(3))) char*)(l), 16, 0, 0);
}

// ---------------- weight transpose + cast: in fp32 [R,C] -> out bf16 [C,R] -------------
__global__ __launch_bounds__(256) void transpose_cast_kernel(
    const float* __restrict__ in, bf16* __restrict__ out, int R, int C) {
  __shared__ float tile[32][33];
  const size_t boff = (size_t)blockIdx.z * R * C;
  in += boff; out += boff;
  int tx = threadIdx.x, ty = threadIdx.y;
  int c0 = blockIdx.x * 32, r0 = blockIdx.y * 32;
#pragma unroll
  for (int j = 0; j < 32; j += 8)
    tile[ty + j][tx] = in[(size_t)(r0 + ty + j) * C + c0 + tx];
  __syncthreads();
#pragma unroll
  for (int j = 0; j < 32; j += 8)
    out[(size_t)(c0 + ty + j) * R + r0 + tx] = (bf16)tile[tx][ty + j];
}

// ---------------- MFMA GEMM, LDS-staged with XOR-swizzled k-groups (conflict-free).
// grid.x = m-tile, grid.y = n-tile (same-A blocks land on same XCD via %8).
// C = A[M,K] @ Bt[N,K]^T + bias. MODE0: gelu -> bf16. MODE1: bf16 + colsum atomics.
template <int BM, int BN, int WM, int WN, int MODE>
__global__ __launch_bounds__(256) void gemm_kernel(
    const bf16* __restrict__ A, const bf16* __restrict__ Bt,
    const float* __restrict__ bias, bf16* __restrict__ outb,
    float* __restrict__ gsum, int N, int K) {
  constexpr int MI = WM / 16, NI = WN / 16, NWC = BN / WN;
  __shared__ bf16 As[BM * 64];
  __shared__ bf16 Bs[BN * 64];
  const int tid = threadIdx.x, l = tid & 63, w = tid >> 6;
  const int wr = w / NWC, wc = w % NWC;
  const int m0 = blockIdx.x * BM, n0 = blockIdx.y * BN;
  const int lrow8 = l >> 3;
  const int lcol8 = (((l & 7) ^ lrow8) * 8);  // XOR-swizzled k-group for staging
  const int quad = l >> 4, lane16 = l & 15;
  const int r7 = lane16 & 7;

  floatx4 acc[MI][NI];
#pragma unroll
  for (int mi = 0; mi < MI; ++mi)
#pragma unroll
    for (int ni = 0; ni < NI; ++ni) acc[mi][ni] = (floatx4){0.f, 0.f, 0.f, 0.f};

  const bf16* gA = A + (size_t)m0 * K;
  const bf16* gB = Bt + (size_t)n0 * K;

  for (int k0 = 0; k0 < K; k0 += 64) {
#pragma unroll
    for (int i = 0; i < BM / 32; ++i) {
      int rb = w * (BM / 4) + i * 8;
      gload_lds16(gA + (size_t)(rb + lrow8) * K + k0 + lcol8, As + rb * 64);
    }
#pragma unroll
    for (int i = 0; i < BN / 32; ++i) {
      int rb = w * (BN / 4) + i * 8;
      gload_lds16(gB + (size_t)(rb + lrow8) * K + k0 + lcol8, Bs + rb * 64);
    }
    __syncthreads();
#pragma unroll
    for (int kk = 0; kk < 64; kk += 32) {
      const int g = (kk >> 3) + quad;  // k-group 0..7
      bf16x8 af[MI], bfv[NI];
#pragma unroll
      for (int mi = 0; mi < MI; ++mi) {
        int r = wr * WM + mi * 16 + lane16;
        af[mi] = *(const bf16x8*)(As + r * 64 + ((g ^ r7) * 8));
      }
#pragma unroll
      for (int ni = 0; ni < NI; ++ni) {
        int r = wc * WN + ni * 16 + lane16;
        bfv[ni] = *(const bf16x8*)(Bs + r * 64 + ((g ^ r7) * 8));
      }
#pragma unroll
      for (int mi = 0; mi < MI; ++mi)
#pragma unroll
        for (int ni = 0; ni < NI; ++ni)
          acc[mi][ni] = __builtin_amdgcn_mfma_f32_16x16x32_bf16(af[mi], bfv[ni], acc[mi][ni], 0, 0, 0);
    }
    __syncthreads();
  }

  float psum[NI];
#pragma unroll
  for (int ni = 0; ni < NI; ++ni) psum[ni] = 0.f;

#pragma unroll
  for (int ni = 0; ni < NI; ++ni) {
    const int gn = n0 + wc * WN + ni * 16 + lane16;
    const float bv = bias[gn];
#pragma unroll
    for (int mi = 0; mi < MI; ++mi) {
#pragma unroll
      for (int i = 0; i < 4; ++i) {
        const int gm = m0 + wr * WM + mi * 16 + quad * 4 + i;
        float v = acc[mi][ni][i] + bv;
        if constexpr (MODE == 0) {
          float ge = 0.5f * v * (1.f + erff(v * 0.7071067811865475f));
          outb[(size_t)gm * N + gn] = (bf16)ge;
        } else {
          outb[(size_t)gm * N + gn] = (bf16)v;
          psum[ni] += v;
        }
      }
    }
  }
  if constexpr (MODE == 1) {
    float* cs = (float*)As;
    __syncthreads();
    for (int t = tid; t < BN; t += 256) cs[t] = 0.f;
    __syncthreads();
#pragma unroll
    for (int ni = 0; ni < NI; ++ni)
      atomicAdd(&cs[wc * WN + ni * 16 + lane16], psum[ni]);
    __syncthreads();
    for (int t = tid; t < BN; t += 256) atomicAdd(&gsum[n0 + t], cs[t]);
  }
}

// ---------------- split-K atomic GEMV: out[z,col] += alpha * sum_k v[z,k]*M[z][k*N+col]
__global__ __launch_bounds__(256) void gemv_kernel(
    const float* __restrict__ vin, int vstride, const float* __restrict__ M,
    size_t mstride, int K, int N, float alpha, float* __restrict__ outp,
    int ostride) {
  const int l = threadIdx.x & 63, wv = threadIdx.x >> 6;
  const int col = blockIdx.x * 64 + l;
  const int KS = gridDim.y;
  const int Kc = (K + KS - 1) / KS;
  const int k0 = blockIdx.y * Kc;
  const int k1 = min(K, k0 + Kc);
  const float* v = vin + (size_t)blockIdx.z * vstride;
  const float* Mp = M + (size_t)blockIdx.z * mstride;
  float acc = 0.f;
  for (int k = k0 + wv; k < k1; k += 4)
    acc += v[k] * Mp[(size_t)k * N + col];
  __shared__ float sh[4][64];
  sh[wv][l] = acc;
  __syncthreads();
  if (wv == 0) {
    float r = (sh[0][l] + sh[1][l] + sh[2][l] + sh[3][l]) * alpha;
    atomicAdd(&outp[(size_t)blockIdx.z * ostride + col], r);
  }
}

// ---------------- fused small gemvs after GEMM2: gate_pre (z=0,1) and ubuf (z=2..4)
__global__ __launch_bounds__(256) void small_gemvs_kernel(
    const float* __restrict__ regs, const float* __restrict__ summary,
    const float* __restrict__ gwp, const float* __restrict__ gbp,
    const float* __restrict__ wpp, float* __restrict__ gate_pre,
    float* __restrict__ ubuf) {
  const int z = blockIdx.z;
  const float* v;
  const float* M;
  float* outp;
  int K, N;
  float alpha;
  if (z == 0)      { v = regs;    M = gwp;             outp = gate_pre; K = 768; N = 512; alpha = 1.f; }
  else if (z == 1) { v = summary; M = gwp + 768 * 512; outp = gate_pre; K = 512; N = 512; alpha = 1.f / 8192.f; }
  else { int r = z - 2; v = summary; M = wpp + (size_t)r * 512 * 256; outp = ubuf + r * 256; K = 512; N = 256; alpha = 1.f / 8192.f; }
  const int l = threadIdx.x & 63, wv = threadIdx.x >> 6;
  const int col = blockIdx.x * 64 + l;
  if (blockIdx.x * 64 >= N) return;  // block-uniform guard
  const int Kc = K / 8;
  const int k0 = blockIdx.y * Kc, k1 = k0 + Kc;
  float acc = 0.f;
  for (int k = k0 + wv; k < k1; k += 4)
    acc += v[k] * M[(size_t)k * N + col];
  __shared__ float sh[4][64];
  sh[wv][l] = acc;
  __syncthreads();
  if (wv == 0) {
    float r = (sh[0][l] + sh[1][l] + sh[2][l] + sh[3][l]) * alpha;
    if (z == 0 && blockIdx.y == 0) r += gbp[col];
    atomicAdd(&outp[col], r);
  }
}

// ---------------- init helper: a[na]=0, b[nb]=0, c[nc]=csrc?csrc:0
__global__ __launch_bounds__(256) void init3_kernel(
    float* __restrict__ a, int na, float* __restrict__ b, int nb,
    float* __restrict__ c, const float* __restrict__ csrc, int nc) {
  const int t = blockIdx.x * 256 + threadIdx.x;
  if (t < na) a[t] = 0.f;
  if (t < nb) b[t] = 0.f;
  if (t < nc) c[t] = csrc ? csrc[t] : 0.f;
}

// ---------------- standalone LN + cast (first phase only); block 0 zeroes phase buffers
__global__ __launch_bounds__(256) void ln_cast_kernel(
    const float* __restrict__ res, const float* __restrict__ s,
    const float* __restrict__ b, bf16* __restrict__ xn,
    float* __restrict__ summary, float* __restrict__ gp0,
    float* __restrict__ gp1, float* __restrict__ ubuf) {
  if (blockIdx.x == 0) {
    const int t = threadIdx.x;
    summary[t] = 0.f; summary[t + 256] = 0.f;
    gp0[t] = 0.f; gp0[t + 256] = 0.f;
    gp1[t] = 0.f; gp1[t + 256] = 0.f;
    ubuf[t] = 0.f; ubuf[t + 256] = 0.f; ubuf[t + 512] = 0.f;
  }
  const int wid = threadIdx.x >> 6, l = threadIdx.x & 63;
  const int row = blockIdx.x * 4 + wid;
  const int cb = l * 8;
  const float* x = res + (size_t)row * 512 + cb;
  float4 a0 = *(const float4*)x, a1 = *(const float4*)(x + 4);
  float v[8] = {a0.x, a0.y, a0.z, a0.w, a1.x, a1.y, a1.z, a1.w};
  float sum = 0.f, sq = 0.f;
#pragma unroll
  for (int j = 0; j < 8; ++j) { sum += v[j]; sq += v[j] * v[j]; }
  sum = wave_red_sum(sum); sq = wave_red_sum(sq);
  float m = sum * (1.f / 512.f);
  float rstd = rsqrtf(sq * (1.f / 512.f) - m * m + EPS);
  bf16x8 o;
#pragma unroll
  for (int j = 0; j < 8; ++j) o[j] = (bf16)((v[j] - m) * rstd * s[cb + j] + b[cb + j]);
  *(bf16x8*)(xn + (size_t)row * 512 + cb) = o;
}

// ---------------- fused residual update + LN/cast for the NEXT phase
__global__ __launch_bounds__(256) void resid_ln_kernel(
    float* __restrict__ res, const bf16* __restrict__ delta,
    const float* __restrict__ gp, const float* __restrict__ passw, int p,
    const float* __restrict__ s, const float* __restrict__ b,
    bf16* __restrict__ xn) {
  const int wid = threadIdx.x >> 6, l = threadIdx.x & 63;
  const int row = blockIdx.x * 4 + wid;
  const int cb = l * 8;
  const float pw = passw[p];
  float* x = res + (size_t)row * 512 + cb;
  float4 a0 = *(const float4*)x, a1 = *(const float4*)(x + 4);
  bf16x8 dv = *(const bf16x8*)(delta + (size_t)row * 512 + cb);
  float4 g0 = *(const float4*)(gp + cb), g1 = *(const float4*)(gp + cb + 4);
  float gg[8] = {g0.x, g0.y, g0.z, g0.w, g1.x, g1.y, g1.z, g1.w};
  float v[8] = {a0.x, a0.y, a0.z, a0.w, a1.x, a1.y, a1.z, a1.w};
#pragma unroll
  for (int j = 0; j < 8; ++j) v[j] += pw * sigmoidf(gg[j]) * (float)dv[j];
  *(float4*)x = make_float4(v[0], v[1], v[2], v[3]);
  *(float4*)(x + 4) = make_float4(v[4], v[5], v[6], v[7]);
  float sum = 0.f, sq = 0.f;
#pragma unroll
  for (int j = 0; j < 8; ++j) { sum += v[j]; sq += v[j] * v[j]; }
  sum = wave_red_sum(sum); sq = wave_red_sum(sq);
  float m = sum * (1.f / 512.f);
  float rstd = rsqrtf(sq * (1.f / 512.f) - m * m + EPS);
  bf16x8 o;
#pragma unroll
  for (int j = 0; j < 8; ++j) o[j] = (bf16)((v[j] - m) * rstd * s[cb + j] + b[cb + j]);
  *(bf16x8*)(xn + (size_t)row * 512 + cb) = o;
}

// ---------------- attention logits: one wave per row; block 0 zeroes c[2048]
__global__ __launch_bounds__(256) void attn_logits_kernel(
    const float* __restrict__ res, const float* __restrict__ s,
    const float* __restrict__ b, const float* __restrict__ kq,
    float* __restrict__ logits, float* __restrict__ czero) {
  if (blockIdx.x == 0) {
#pragma unroll
    for (int j = 0; j < 8; ++j) czero[threadIdx.x * 8 + j] = 0.f;
  }
  const int wid = threadIdx.x >> 6, l = threadIdx.x & 63;
  const int row = blockIdx.x * 4 + wid;
  const int cb = l * 8;
  const float* x = res + (size_t)row * 512 + cb;
  float4 a0 = *(const float4*)x, a1 = *(const float4*)(x + 4);
  float v[8] = {a0.x, a0.y, a0.z, a0.w, a1.x, a1.y, a1.z, a1.w};
  float sum = 0.f, sq = 0.f;
#pragma unroll
  for (int j = 0; j < 8; ++j) { sum += v[j]; sq += v[j] * v[j]; }
  sum = wave_red_sum(sum); sq = wave_red_sum(sq);
  float m = sum * (1.f / 512.f);
  float rstd = rsqrtf(sq * (1.f / 512.f) - m * m + EPS);
  float dot = 0.f;
#pragma unroll
  for (int j = 0; j < 8; ++j)
    dot += ((v[j] - m) * rstd * s[cb + j] + b[cb + j]) * kq[cb + j];
  dot = wave_red_sum(dot);
  if (l == 0) logits[row] = dot;
}

// ---------------- softmax over 2048 per batch
__global__ __launch_bounds__(256) void softmax_kernel(float* __restrict__ attn) {
  __shared__ float red[4];
  const int t = threadIdx.x;
  float* p = attn + blockIdx.x * 2048;
  float v[8];
#pragma unroll
  for (int j = 0; j < 8; ++j) v[j] = p[t * 8 + j];
  float mx = v[0];
#pragma unroll
  for (int j = 1; j < 8; ++j) mx = fmaxf(mx, v[j]);
  mx = wave_red_max(mx);
  if ((t & 63) == 0) red[t >> 6] = mx;
  __syncthreads();
  mx = fmaxf(fmaxf(red[0], red[1]), fmaxf(red[2], red[3]));
  __syncthreads();
  float s = 0.f;
#pragma unroll
  for (int j = 0; j < 8; ++j) { v[j] = expf(v[j] - mx); s += v[j]; }
  s = wave_red_sum(s);
  if ((t & 63) == 0) red[t >> 6] = s;
  __syncthreads();
  float inv = 1.f / (red[0] + red[1] + red[2] + red[3]);
#pragma unroll
  for (int j = 0; j < 8; ++j) p[t * 8 + j] = v[j] * inv;
}

// ---------------- weighted row-sum of LN(res); attn==null -> uniform 1/2048
__global__ __launch_bounds__(256) void wsum_kernel(
    const float* __restrict__ res, const float* __restrict__ s,
    const float* __restrict__ b, const float* __restrict__ attn,
    float* __restrict__ cout, int per_batch) {
  __shared__ float csh[512];
  const int tid = threadIdx.x, l = tid & 63, wv = tid >> 6;
  for (int t = tid; t < 512; t += 256) csh[t] = 0.f;
  __syncthreads();
  const int cb = l * 8;
  float sl[8], bl[8];
#pragma unroll
  for (int j = 0; j < 8; ++j) { sl[j] = s[cb + j]; bl[j] = b[cb + j]; }
  float pf[8] = {};
  const int base_row = blockIdx.x * 32;
  for (int rr = wv; rr < 32; rr += 4) {
    int row = base_row + rr;
    const float* x = res + (size_t)row * 512 + cb;
    float4 a0 = *(const float4*)x, a1 = *(const float4*)(x + 4);
    float v[8] = {a0.x, a0.y, a0.z, a0.w, a1.x, a1.y, a1.z, a1.w};
    float sum = 0.f, sq = 0.f;
#pragma unroll
    for (int j = 0; j < 8; ++j) { sum += v[j]; sq += v[j] * v[j]; }
    sum = wave_red_sum(sum); sq = wave_red_sum(sq);
    float m = sum * (1.f / 512.f);
    float rstd = rsqrtf(sq * (1.f / 512.f) - m * m + EPS);
    float aw = attn ? attn[row] : (1.f / 2048.f);
#pragma unroll
    for (int j = 0; j < 8; ++j) pf[j] += aw * ((v[j] - m) * rstd * sl[j] + bl[j]);
  }
#pragma unroll
  for (int j = 0; j < 8; ++j) atomicAdd(&csh[cb + j], pf[j]);
  __syncthreads();
  float* outp = cout + (per_batch ? (blockIdx.x >> 6) * 512 : 0);
  for (int t = tid; t < 512; t += 256) atomicAdd(&outp[t], csh[t]);
}

// ---------------- kq = scale * (KM @ q), one wave per row
__global__ __launch_bounds__(256) void kq_kernel(
    const float* __restrict__ KM, const float* __restrict__ q, float scale,
    float* __restrict__ kq) {
  const int d = blockIdx.x * 4 + (threadIdx.x >> 6), l = threadIdx.x & 63;
  float a = 0.f;
  for (int j = l; j < 512; j += 64) a += KM[(size_t)d * 512 + j] * q[j];
  a = wave_red_sum(a);
  if (l == 0) kq[d] = a * scale;
}

// ---------------- regsB = regsA + wg*ubuf; then zero summary/ubuf/gp_next for next phase
__global__ __launch_bounds__(256) void reg_final_kernel(
    const float* __restrict__ regsA, float* __restrict__ ubuf,
    float* __restrict__ summary, const float* __restrict__ wgw,
    const float* __restrict__ wgb, float* __restrict__ regsB,
    float* __restrict__ gp_next) {
  __shared__ float wg[3];
  const int l = threadIdx.x & 63, wv = threadIdx.x >> 6;
  if (wv < 3) {
    float sg = 0.f;
    for (int d = l; d < 512; d += 64) sg += summary[d] * wgw[wv * 512 + d];
    sg = wave_red_sum(sg) * (1.f / 8192.f);
    if (l == 0) wg[wv] = sigmoidf(sg + wgb[wv]);
  }
  __syncthreads();
  for (int j = threadIdx.x; j < 768; j += 256)
    regsB[j] = regsA[j] + wg[j >> 8] * ubuf[j];
  __syncthreads();
  const int t = threadIdx.x;
  summary[t] = 0.f; summary[t + 256] = 0.f;
  gp_next[t] = 0.f; gp_next[t + 256] = 0.f;
  ubuf[t] = 0.f; ubuf[t + 256] = 0.f; ubuf[t + 512] = 0.f;
}

// ---------------- pass_w = sigmoid(tile(reg_init,5) @ ms3_w + ms3_b)
__global__ __launch_bounds__(64) void passw_kernel(
    const float* __restrict__ reg_init, const float* __restrict__ ms3_w,
    const float* __restrict__ ms3_b, float* __restrict__ pass_w) {
  const int l = threadIdx.x;
  float acc[5] = {};
  for (int i = l; i < 3840; i += 64) {
    float v = reg_init[i % 768];
#pragma unroll
    for (int p = 0; p < 5; ++p) acc[p] += v * ms3_w[i * 5 + p];
  }
#pragma unroll
  for (int p = 0; p < 5; ++p) acc[p] = wave_red_sum(acc[p]);
  if (l < 5) pass_w[l] = sigmoidf(acc[l] + ms3_b[l]);
}

// ---------------- final: out = LN(res + outv[b]; out_ln)
__global__ __launch_bounds__(256) void final_out_kernel(
    const float* __restrict__ res, const float* __restrict__ outv,
    const float* __restrict__ s, const float* __restrict__ b,
    float* __restrict__ out) {
  const int wid = threadIdx.x >> 6, l = threadIdx.x & 63;
  const int row = blockIdx.x * 4 + wid;
  const int bidx = row >> 11, cb = l * 8;
  const float* x = res + (size_t)row * 512 + cb;
  const float* ov = outv + bidx * 512 + cb;
  float4 a0 = *(const float4*)x, a1 = *(const float4*)(x + 4);
  float v[8] = {a0.x, a0.y, a0.z, a0.w, a1.x, a1.y, a1.z, a1.w};
#pragma unroll
  for (int j = 0; j < 8; ++j) v[j] += ov[j];
  float sum = 0.f, sq = 0.f;
#pragma unroll
  for (int j = 0; j < 8; ++j) { sum += v[j]; sq += v[j] * v[j]; }
  sum = wave_red_sum(sum); sq = wave_red_sum(sq);
  float m = sum * (1.f / 512.f);
  float rstd = rsqrtf(sq * (1.f / 512.f) - m * m + EPS);
  float o[8];
#pragma unroll
  for (int j = 0; j < 8; ++j) o[j] = (v[j] - m) * rstd * s[cb + j] + b[cb + j];
  float* op = out + (size_t)row * 512 + cb;
  *(float4*)op = make_float4(o[0], o[1], o[2], o[3]);
  *(float4*)(op + 4) = make_float4(o[4], o[5], o[6], o[7]);
}

extern "C" void kernel_launch(void* const* d_in, const int* in_sizes, int n_in,
                              void* d_out, int out_size, void* d_ws, size_t ws_size,
                              hipStream_t stream) {
  const float* x        = (const float*)d_in[0];
  const float* reg_init = (const float*)d_in[1];
  const float* ffn_ln_s = (const float*)d_in[2];
  const float* ffn_ln_b = (const float*)d_in[3];
  const float* ffn_w1   = (const float*)d_in[4];
  const float* ffn_b1   = (const float*)d_in[5];
  const float* ffn_w2   = (const float*)d_in[6];
  const float* ffn_b2   = (const float*)d_in[7];
  const float* gate_w   = (const float*)d_in[8];
  const float* gate_b   = (const float*)d_in[9];
  const float* wproj_w  = (const float*)d_in[10];
  const float* wgate_w  = (const float*)d_in[11];
  const float* wgate_b  = (const float*)d_in[12];
  const float* s4_q     = (const float*)d_in[13];
  const float* s4_k     = (const float*)d_in[14];
  const float* s4_v     = (const float*)d_in[15];
  const float* s4_sum   = (const float*)d_in[16];
  const float* s4_ln_s  = (const float*)d_in[17];
  const float* s4_ln_b  = (const float*)d_in[18];
  const float* ms3_w    = (const float*)d_in[19];
  const float* ms3_b    = (const float*)d_in[20];
  const float* m4_q     = (const float*)d_in[21];
  const float* m4_k     = (const float*)d_in[22];
  const float* m4_v     = (const float*)d_in[23];
  const float* m4_out   = (const float*)d_in[24];
  const float* m4_ln_s  = (const float*)d_in[25];
  const float* m4_ln_b  = (const float*)d_in[26];
  const float* out_ln_s = (const float*)d_in[27];
  const float* out_ln_b = (const float*)d_in[28];
  float* out = (float*)d_out;

  char* wsp = (char*)d_ws;
  auto take = [&](size_t n) { char* p = wsp; wsp += (n + 255) & ~(size_t)255; return p; };
  float* residual = (float*)take(8192ull * 512 * 4);
  bf16*  xn       = (bf16*) take(8192ull * 512 * 2);
  bf16*  hbuf     = (bf16*) take(8192ull * 1536 * 2);
  bf16*  delta    = (bf16*) take(8192ull * 512 * 2);
  bf16*  w1t      = (bf16*) take(3ull * 1536 * 512 * 2);
  bf16*  w2t      = (bf16*) take(3ull * 512 * 1536 * 2);
  float* attn     = (float*)take(8192 * 4);
  float* cacc     = (float*)take(2048 * 4);
  float* qbuf     = (float*)take(512 * 4);
  float* kqbuf    = (float*)take(512 * 4);
  float* summary  = (float*)take(512 * 4);
  float* gp0      = (float*)take(512 * 4);
  float* gp1      = (float*)take(512 * 4);
  float* ubuf     = (float*)take(768 * 4);
  float* regsA    = (float*)take(768 * 4);
  float* regsB    = (float*)take(768 * 4);
  float* banks    = (float*)take(5 * 768 * 4);
  float* passw    = (float*)take(64);
  float* summv    = (float*)take(4 * 512 * 4);
  float* outv     = (float*)take(4 * 512 * 4);
  float* gpbuf[2] = {gp0, gp1};

  hipMemcpyAsync(residual, x, 8192ull * 512 * 4, hipMemcpyDeviceToDevice, stream);
  transpose_cast_kernel<<<dim3(1536 / 32, 512 / 32, 3), dim3(32, 8), 0, stream>>>(ffn_w1, w1t, 512, 1536);
  transpose_cast_kernel<<<dim3(512 / 32, 1536 / 32, 3), dim3(32, 8), 0, stream>>>(ffn_w2, w2t, 1536, 512);
  passw_kernel<<<1, 64, 0, stream>>>(reg_init, ms3_w, ms3_b, passw);
  // first-phase LN + zero phase buffers
  ln_cast_kernel<<<2048, 256, 0, stream>>>(residual, ffn_ln_s, ffn_ln_b, xn, summary, gp0, gp1, ubuf);

  const float scale = 0.04419417382415922f;  // 512^-0.5

  for (int p = 0; p < 5; ++p) {
    // s4_read
    if (p == 0) {
      // q = 0 exactly -> uniform attention; just zero cacc/summv, regsA=reg_init
      init3_kernel<<<8, 256, 0, stream>>>(cacc, 2048, summv, 512, regsA, reg_init, 768);
      wsum_kernel<<<256, 256, 0, stream>>>(residual, s4_ln_s, s4_ln_b, nullptr, cacc, 0);
    } else {
      init3_kernel<<<8, 256, 0, stream>>>(qbuf, 512, summv, 512, regsA, reg_init, 768);
      gemv_kernel<<<dim3(8, 4 * (p + 1), 1), 256, 0, stream>>>(banks, 0, s4_q, 0, p * 768, 512, 1.f, qbuf, 0);
      kq_kernel<<<128, 256, 0, stream>>>(s4_k, qbuf, scale, kqbuf);
      attn_logits_kernel<<<2048, 256, 0, stream>>>(residual, s4_ln_s, s4_ln_b, kqbuf, attn, cacc);
      softmax_kernel<<<4, 256, 0, stream>>>(attn);
      wsum_kernel<<<256, 256, 0, stream>>>(residual, s4_ln_s, s4_ln_b, attn, cacc, 0);
    }
    gemv_kernel<<<dim3(8, 8, 1), 256, 0, stream>>>(cacc, 0, s4_v, 0, 512, 512, 0.25f, summv, 0);
    gemv_kernel<<<dim3(12, 8, 1), 256, 0, stream>>>(summv, 0, s4_sum, 0, 512, 768, 1.f, regsA, 0);

    float* cur = regsA;
    float* nxt = regsB;
    for (int ph = 0; ph < 3; ++ph) {
      const int pp = p * 3 + ph;
      gemm_kernel<128, 128, 64, 64, 0><<<dim3(64, 12), 256, 0, stream>>>(
          xn, w1t + (size_t)ph * 1536 * 512, ffn_b1 + ph * 1536, hbuf, nullptr, 1536, 512);
      gemm_kernel<128, 64, 64, 32, 1><<<dim3(64, 8), 256, 0, stream>>>(
          hbuf, w2t + (size_t)ph * 512 * 1536, ffn_b2 + ph * 512, delta, summary, 512, 1536);
      small_gemvs_kernel<<<dim3(8, 8, 5), 256, 0, stream>>>(
          cur, summary, gate_w + (size_t)pp * 1280 * 512, gate_b + pp * 512,
          wproj_w + (size_t)pp * 3 * 512 * 256, gpbuf[pp & 1], ubuf);
      float* nx = (ph == 2) ? (banks + p * 768) : nxt;
      reg_final_kernel<<<1, 256, 0, stream>>>(cur, ubuf, summary, wgate_w + pp * 3 * 512,
                                              wgate_b + pp * 3, nx, gpbuf[(pp + 1) & 1]);
      // fused residual update + LN for next phase ((ph+1)%3; at pp=14 output unused)
      const int nph = (ph + 1) % 3;
      resid_ln_kernel<<<2048, 256, 0, stream>>>(residual, delta, gpbuf[pp & 1], passw, p,
                                                ffn_ln_s + nph * 512, ffn_ln_b + nph * 512, xn);
      float* t = cur; cur = nx; nxt = (ph == 0) ? regsA : regsB; (void)t;
    }
  }

  // MetaS4
  init3_kernel<<<8, 256, 0, stream>>>(qbuf, 512, summv, 2048, outv, nullptr, 2048);
  gemv_kernel<<<dim3(8, 16, 1), 256, 0, stream>>>(banks, 0, m4_q, 0, 3840, 512, 1.f, qbuf, 0);
  kq_kernel<<<128, 256, 0, stream>>>(m4_k, qbuf, scale, kqbuf);
  attn_logits_kernel<<<2048, 256, 0, stream>>>(residual, m4_ln_s, m4_ln_b, kqbuf, attn, cacc);
  softmax_kernel<<<4, 256, 0, stream>>>(attn);
  wsum_kernel<<<256, 256, 0, stream>>>(residual, m4_ln_s, m4_ln_b, attn, cacc, 1);
  gemv_kernel<<<dim3(8, 8, 4), 256, 0, stream>>>(cacc, 512, m4_v, 0, 512, 512, 1.f, summv, 512);
  gemv_kernel<<<dim3(8, 8, 4), 256, 0, stream>>>(summv, 512, m4_out, 0, 512, 512, 1.f, outv, 512);
  final_out_kernel<<<2048, 256, 0, stream>>>(residual, outv, out_ln_s, out_ln_b, out);
}